// Round 2
// baseline (31.495 us; speedup 1.0000x reference)
//
#include <hip/hip_runtime.h>
#include <math.h>

constexpr int B   = 2048;
constexpr int C   = 128;
constexpr int L   = 16384;
constexpr int PAD = 64;   // C/2

typedef float f32x4 __attribute__((ext_vector_type(4)));

__global__ __launch_bounds__(256) void mask_policy_kernel(
    const float* __restrict__ logits,
    const float* __restrict__ u,
    const int*   __restrict__ shift_x,
    float*       __restrict__ out)
{
    __shared__ float  g_sh[C];
    __shared__ float2 bd_sh[C];   // (base, delta) per cell
    __shared__ float  red_sh[2];

    const int b   = blockIdx.x;
    const int tid = threadIdx.x;

    // ---- Phase 1: sample grid row + log_prob (threads 0..127) ----
    float lp = 0.0f;
    if (tid < C) {
        float  x  = logits[tid];
        // p must be (near-)correctly-rounded f32 sigmoid for bit-exact grid bits
        double ed = exp(-(double)x);
        float  p  = (float)(1.0 / (1.0 + ed));
        float  uv = u[(size_t)b * C + tid];
        float  g  = (uv < p) ? 1.0f : 0.0f;
        g_sh[tid] = g;
        // log-prob terms in f32 (output threshold 1.82, f32 error ~1e-5):
        // lsp = log sigmoid(x) = -log1p(e^-x);  lsn = log sigmoid(-x) = lsp - x
        float lsp = -log1pf((float)ed);
        float lsn = lsp - x;
        lp = (g != 0.0f) ? lsp : lsn;
    }
    // wave-64 reduce; waves 0,1 carry data
    float v = lp;
    #pragma unroll
    for (int off = 32; off > 0; off >>= 1) v += __shfl_down(v, off, 64);
    if (tid == 0)  red_sh[0] = v;
    if (tid == 64) red_sh[1] = v;
    __syncthreads();

    if (tid < C) {
        float g0 = g_sh[tid];
        float g1 = g_sh[(tid < C - 1) ? tid + 1 : C - 1];
        bd_sh[tid] = make_float2(g0, g1 - g0);
    }
    if (tid == 0) out[(size_t)B * L + b] = red_sh[0] + red_sh[1];
    __syncthreads();

    // ---- Phase 2: masks row ----
    const int shift = shift_x[b];
    const int s  = shift - PAD;        // t = s + j, s in [-64, 63]
    const int s2 = shift - 2 * PAD;    // tm = t - 64 = j + (shift - 128)

    auto general = [&](int j) -> float {
        int t = s + j;
        if (t < 0)       t = -t;             // reflect low
        else if (t >= L) t = 2 * L - 2 - t;  // reflect high
        float pos = (t + 0.5f) * (1.0f / 128.0f) - 0.5f;
        pos = fmaxf(pos, 0.0f);
        int i0 = (int)pos;                   // floor, pos >= 0
        if (i0 > C - 1) i0 = C - 1;
        float w = pos - (float)i0;
        float2 bd = bd_sh[i0];
        return fmaf(w, bd.y, bd.x);          // g0 + w*(g1-g0), exact for bits
    };

    float* orow = out + (size_t)b * L;

    #pragma unroll
    for (int k = 0; k < L / (256 * 4); ++k) {   // 16 iters
        const int j0 = (k * 256 + tid) * 4;
        f32x4 r;
        if (k > 0 && k < 15) {
            // bulk: no reflection, no clip possible
            const int tm = j0 + s2;            // >= 896, <= 15358
            const int m  = tm >> 7;
            const int rr = tm & 127;
            if (rr <= 124) {                   // all 4 outputs in cell m
                const float2 bd = bd_sh[m];
                const float w0 = (rr + 0.5f) * (1.0f / 128.0f);
                const float v0 = fmaf(w0, bd.y, bd.x);
                const float st = bd.y * (1.0f / 128.0f);
                r.x = v0;
                r.y = v0 + st;
                r.z = v0 + 2.0f * st;
                r.w = v0 + 3.0f * st;
            } else {                           // cell boundary inside the 4
                float vals[4];
                #pragma unroll
                for (int q = 0; q < 4; ++q) {
                    const int tmq = tm + q;
                    const int mq  = tmq >> 7;
                    const int rq  = tmq & 127;
                    const float wq = (rq + 0.5f) * (1.0f / 128.0f);
                    const float2 bd = bd_sh[mq];
                    vals[q] = fmaf(wq, bd.y, bd.x);
                }
                r.x = vals[0]; r.y = vals[1]; r.z = vals[2]; r.w = vals[3];
            }
        } else {
            // edge iterations: full reference formula incl. reflection/clip
            r.x = general(j0);
            r.y = general(j0 + 1);
            r.z = general(j0 + 2);
            r.w = general(j0 + 3);
        }
        __builtin_nontemporal_store(r, reinterpret_cast<f32x4*>(orow + j0));
    }
}

extern "C" void kernel_launch(void* const* d_in, const int* in_sizes, int n_in,
                              void* d_out, int out_size, void* d_ws, size_t ws_size,
                              hipStream_t stream) {
    const float* logits  = (const float*)d_in[0];
    const float* u       = (const float*)d_in[1];
    const int*   shift_x = (const int*)d_in[2];
    float*       out     = (float*)d_out;

    mask_policy_kernel<<<B, 256, 0, stream>>>(logits, u, shift_x, out);
}

// Round 3
// 26.242 us; speedup vs baseline: 1.2002x; 1.2002x over previous
//
#include <hip/hip_runtime.h>
#include <math.h>

constexpr int B   = 2048;
constexpr int C   = 128;
constexpr int L   = 16384;
constexpr int PAD = 64;   // C/2

__global__ __launch_bounds__(256) void mask_policy_kernel(
    const float* __restrict__ logits,
    const float* __restrict__ u,
    const int*   __restrict__ shift_x,
    float*       __restrict__ out)
{
    __shared__ float  g_sh[C];
    __shared__ float2 bd_sh[C];   // (base, delta) per cell
    __shared__ float  red_sh[2];

    const int b   = blockIdx.x;
    const int tid = threadIdx.x;

    // ---- Phase 1: sample grid row + log_prob (threads 0..127) ----
    float lp = 0.0f;
    if (tid < C) {
        float  x  = logits[tid];
        // p must be (near-)correctly-rounded f32 sigmoid for bit-exact grid bits
        double ed = exp(-(double)x);
        float  p  = (float)(1.0 / (1.0 + ed));
        float  uv = u[(size_t)b * C + tid];
        float  g  = (uv < p) ? 1.0f : 0.0f;
        g_sh[tid] = g;
        // log-prob terms in f32 (output threshold 1.82, f32 error ~1e-5):
        // lsp = log sigmoid(x) = -log1p(e^-x);  lsn = log sigmoid(-x) = lsp - x
        float lsp = -log1pf((float)ed);
        float lsn = lsp - x;
        lp = (g != 0.0f) ? lsp : lsn;
    }
    // wave-64 reduce; waves 0,1 carry data
    float v = lp;
    #pragma unroll
    for (int off = 32; off > 0; off >>= 1) v += __shfl_down(v, off, 64);
    if (tid == 0)  red_sh[0] = v;
    if (tid == 64) red_sh[1] = v;
    __syncthreads();

    if (tid < C) {
        float g0 = g_sh[tid];
        float g1 = g_sh[(tid < C - 1) ? tid + 1 : C - 1];
        bd_sh[tid] = make_float2(g0, g1 - g0);
    }
    if (tid == 0) out[(size_t)B * L + b] = red_sh[0] + red_sh[1];
    __syncthreads();

    // ---- Phase 2: masks row ----
    const int shift = shift_x[b];
    const int s  = shift - PAD;        // t = s + j, s in [-64, 63]
    const int s2 = shift - 2 * PAD;    // tm = t - 64 = j + (shift - 128)

    auto general = [&](int j) -> float {
        int t = s + j;
        if (t < 0)       t = -t;             // reflect low
        else if (t >= L) t = 2 * L - 2 - t;  // reflect high
        float pos = (t + 0.5f) * (1.0f / 128.0f) - 0.5f;
        pos = fmaxf(pos, 0.0f);
        int i0 = (int)pos;                   // floor, pos >= 0
        if (i0 > C - 1) i0 = C - 1;
        float w = pos - (float)i0;
        float2 bd = bd_sh[i0];
        return fmaf(w, bd.y, bd.x);          // g0 + w*(g1-g0), exact for bits
    };

    float* orow = out + (size_t)b * L;

    #pragma unroll
    for (int k = 0; k < L / (256 * 4); ++k) {   // 16 iters
        const int j0 = (k * 256 + tid) * 4;
        float4 r;
        if (k > 0 && k < 15) {
            // bulk: no reflection, no clip possible
            const int tm = j0 + s2;            // >= 896, <= 15358
            const int m  = tm >> 7;
            const int rr = tm & 127;
            if (rr <= 124) {                   // all 4 outputs in cell m
                const float2 bd = bd_sh[m];
                const float w0 = (rr + 0.5f) * (1.0f / 128.0f);
                const float v0 = fmaf(w0, bd.y, bd.x);
                const float st = bd.y * (1.0f / 128.0f);
                r.x = v0;
                r.y = v0 + st;
                r.z = v0 + 2.0f * st;
                r.w = v0 + 3.0f * st;
            } else {                           // cell boundary inside the 4
                float vals[4];
                #pragma unroll
                for (int q = 0; q < 4; ++q) {
                    const int tmq = tm + q;
                    const int mq  = tmq >> 7;
                    const int rq  = tmq & 127;
                    const float wq = (rq + 0.5f) * (1.0f / 128.0f);
                    const float2 bd = bd_sh[mq];
                    vals[q] = fmaf(wq, bd.y, bd.x);
                }
                r.x = vals[0]; r.y = vals[1]; r.z = vals[2]; r.w = vals[3];
            }
        } else {
            // edge iterations: full reference formula incl. reflection/clip
            r.x = general(j0);
            r.y = general(j0 + 1);
            r.z = general(j0 + 2);
            r.w = general(j0 + 3);
        }
        *reinterpret_cast<float4*>(orow + j0) = r;
    }
}

extern "C" void kernel_launch(void* const* d_in, const int* in_sizes, int n_in,
                              void* d_out, int out_size, void* d_ws, size_t ws_size,
                              hipStream_t stream) {
    const float* logits  = (const float*)d_in[0];
    const float* u       = (const float*)d_in[1];
    const int*   shift_x = (const int*)d_in[2];
    float*       out     = (float*)d_out;

    mask_policy_kernel<<<B, 256, 0, stream>>>(logits, u, shift_x, out);
}

// Round 4
// 26.129 us; speedup vs baseline: 1.2054x; 1.0043x over previous
//
#include <hip/hip_runtime.h>
#include <math.h>

constexpr int B    = 2048;
constexpr int C    = 128;
constexpr int L    = 16384;
constexpr int PAD  = 64;     // C/2
constexpr int ROWS = 4;      // rows per block
constexpr int NBLK = B / ROWS;   // 512 blocks, 2/CU, all resident

__global__ __launch_bounds__(1024) void mask_policy_kernel(
    const float* __restrict__ logits,
    const float* __restrict__ u,
    const int*   __restrict__ shift_x,
    float*       __restrict__ out)
{
    __shared__ float g_sh[ROWS][C + 4];   // [..][128] duplicates [..][127] (i1 clamp)
    __shared__ float red_sh[ROWS][2];

    const int tid = threadIdx.x;
    const int tg  = tid >> 8;            // row group 0..3 (4 waves each)
    const int t   = tid & 255;           // thread within group
    const int row = blockIdx.x * ROWS + tg;

    const int shift = shift_x[row];      // issue early (wave-uniform per group)

    // ---- Prefix: sample grid row; keep log-prob term in a register ----
    float lp = 0.0f;
    if (t < C) {
        float  uv = u[(size_t)row * C + t];          // issue load first
        float  x  = logits[t];
        double ed = exp(-(double)x);                 // correctly-rounded f32 sigmoid
        float  p  = (float)(1.0 / (1.0 + ed));
        float  g  = (uv < p) ? 1.0f : 0.0f;
        g_sh[tg][t] = g;
        if (t == C - 1) g_sh[tg][C] = g;             // pad: clamp i1=min(i0+1,127)
        float lsp = -log1pf((float)ed);              // log sigmoid(x)
        lp = (g != 0.0f) ? lsp : (lsp - x);          // log sigmoid(-x) = lsp - x
    }
    __syncthreads();   // single barrier before stores

    // ---- Phase 2: masks row ----
    const int s  = shift - PAD;        // t_out = s + j, s in [-64, 63]
    const int s2 = shift - 2 * PAD;    // tm = j + (shift - 128)
    const float* __restrict__ g = g_sh[tg];
    float* orow = out + (size_t)row * L;

    auto general = [&](int j) -> float {
        int tt = s + j;
        if (tt < 0)       tt = -tt;              // reflect low
        else if (tt >= L) tt = 2 * L - 2 - tt;   // reflect high
        float pos = (tt + 0.5f) * (1.0f / 128.0f) - 0.5f;
        pos = fmaxf(pos, 0.0f);
        int i0 = (int)pos;
        if (i0 > C - 1) i0 = C - 1;
        float w  = pos - (float)i0;
        float g0 = g[i0];
        float g1 = g[i0 + 1];                    // pad handles i0==127
        return fmaf(w, g1 - g0, g0);
    };

    #pragma unroll
    for (int k = 0; k < 16; ++k) {
        const int j0 = (k * 256 + t) * 4;
        float4 r;
        if (k > 0 && k < 15) {
            // bulk: no reflection/clip possible (tm in [896, 15358])
            const int m  = (j0 + s2) >> 7;
            const int rr = (j0 + s2) & 127;
            if (rr <= 124) {                     // all 4 outputs in cell m
                const float g0 = g[m];
                const float d  = g[m + 1] - g0;
                const float w0 = (rr + 0.5f) * (1.0f / 128.0f);
                const float v0 = fmaf(w0, d, g0);
                const float st = d * (1.0f / 128.0f);
                r.x = v0;
                r.y = v0 + st;
                r.z = v0 + 2.0f * st;
                r.w = v0 + 3.0f * st;
            } else {                             // cell boundary inside the 4
                float vals[4];
                #pragma unroll
                for (int q = 0; q < 4; ++q) {
                    const int tmq = j0 + s2 + q;
                    const int mq  = tmq >> 7;
                    const int rq  = tmq & 127;
                    const float wq = (rq + 0.5f) * (1.0f / 128.0f);
                    const float g0 = g[mq];
                    vals[q] = fmaf(wq, g[mq + 1] - g0, g0);
                }
                r.x = vals[0]; r.y = vals[1]; r.z = vals[2]; r.w = vals[3];
            }
        } else {
            r.x = general(j0);
            r.y = general(j0 + 1);
            r.z = general(j0 + 2);
            r.w = general(j0 + 3);
        }
        *reinterpret_cast<float4*>(orow + j0) = r;
    }

    // ---- Epilogue: log-prob reduction (off the critical prefix) ----
    float v = lp;
    #pragma unroll
    for (int off = 32; off > 0; off >>= 1) v += __shfl_down(v, off, 64);
    if (t == 0)  red_sh[tg][0] = v;
    if (t == 64) red_sh[tg][1] = v;
    __syncthreads();
    if (t == 0) out[(size_t)B * L + row] = red_sh[tg][0] + red_sh[tg][1];
}

extern "C" void kernel_launch(void* const* d_in, const int* in_sizes, int n_in,
                              void* d_out, int out_size, void* d_ws, size_t ws_size,
                              hipStream_t stream) {
    const float* logits  = (const float*)d_in[0];
    const float* u       = (const float*)d_in[1];
    const int*   shift_x = (const int*)d_in[2];
    float*       out     = (float*)d_out;

    mask_policy_kernel<<<NBLK, 1024, 0, stream>>>(logits, u, shift_x, out);
}